// Round 3
// baseline (2241.471 us; speedup 1.0000x reference)
//
#include <hip/hip_runtime.h>
#include <math.h>

// AdditiveAttention: B=64, L=1024, Q=K=H=1024, fp32 in/out.
// ZERO-workspace variant: all intermediates live inside d_out (131072 floats),
// in case previous container crashes were ws_size OOB faults.
//
//   out[0..65536):      k1 writes q = query@W1^T here; k3 zeroes it; k4 accumulates context.
//   out[65536..131072): k1 zeroes; k2 atomicAdds scores; k3 overwrites with softmax weights.
//
// Pipeline:
//   k1: q[b,h] = query @ W1^T  (0.13 GFLOP)  + zero score region
//   k2: score[b,l] += sum_{h in 64-block} tanh(q[b,h] + keys[b,l,:]·W2[h,:]) * v[h]
//       fused 65536x1024x1024 GEMM + tanh-dot epilogue  (137 GFLOP, dominant, fp32 VALU)
//   k3: mask -> -inf; softmax over l (in-place); zero context row; inline mask-dtype sniff
//   k4: context[b,k] += sum_l w[b,l]*keys[b,l,k]  (268 MB read, atomicAdd)

// ---------------- k1: q = query @ W1^T (BM=64 b, BN=64 h, BK=32) ----------------
__global__ __launch_bounds__(256) void k1_qproj(
    const float* __restrict__ query, const float* __restrict__ W1,
    float* __restrict__ out)
{
    __shared__ float As[32][64];   // [k][b]
    __shared__ float Bs[32][64];   // [k][h]
    const int t  = threadIdx.x;
    const int tx = t & 15, ty = t >> 4;
    const int h0 = blockIdx.x * 64;

    // zero the score region: 16 blocks x 256 threads x 4 float4 = 65536 floats
    {
        const float4 z = {0.f, 0.f, 0.f, 0.f};
        float4* sz = (float4*)(out + 65536) + (blockIdx.x * 256 + t) * 4;
        sz[0] = z; sz[1] = z; sz[2] = z; sz[3] = z;
    }

    const int sr = t >> 2;          // staging row 0..63
    const int sk = (t & 3) * 8;     // staging k offset {0,8,16,24}
    float c[4][4] = {{0.f}};
    for (int k0 = 0; k0 < 1024; k0 += 32) {
        const float4 a0 = *(const float4*)(query + sr * 1024 + k0 + sk);
        const float4 a1 = *(const float4*)(query + sr * 1024 + k0 + sk + 4);
        const float4 b0 = *(const float4*)(W1 + (h0 + sr) * 1024 + k0 + sk);
        const float4 b1 = *(const float4*)(W1 + (h0 + sr) * 1024 + k0 + sk + 4);
        __syncthreads();
        As[sk+0][sr]=a0.x; As[sk+1][sr]=a0.y; As[sk+2][sr]=a0.z; As[sk+3][sr]=a0.w;
        As[sk+4][sr]=a1.x; As[sk+5][sr]=a1.y; As[sk+6][sr]=a1.z; As[sk+7][sr]=a1.w;
        Bs[sk+0][sr]=b0.x; Bs[sk+1][sr]=b0.y; Bs[sk+2][sr]=b0.z; Bs[sk+3][sr]=b0.w;
        Bs[sk+4][sr]=b1.x; Bs[sk+5][sr]=b1.y; Bs[sk+6][sr]=b1.z; Bs[sk+7][sr]=b1.w;
        __syncthreads();
        #pragma unroll
        for (int k = 0; k < 32; ++k) {
            const float4 av = *(const float4*)&As[k][ty*4];
            const float4 bv = *(const float4*)&Bs[k][tx*4];
            const float aa[4] = {av.x, av.y, av.z, av.w};
            const float bb[4] = {bv.x, bv.y, bv.z, bv.w};
            #pragma unroll
            for (int i = 0; i < 4; ++i)
                #pragma unroll
                for (int j = 0; j < 4; ++j)
                    c[i][j] = fmaf(aa[i], bb[j], c[i][j]);
        }
    }
    // q lives in the context region out[0..65536) until k3 reclaims it
    #pragma unroll
    for (int i = 0; i < 4; ++i)
        #pragma unroll
        for (int j = 0; j < 4; ++j)
            out[(ty*4 + i) * 1024 + h0 + tx*4 + j] = c[i][j];
}

// --------- k2: fused keys@W2^T GEMM + tanh-dot-v reduction over h ---------
// grid: (hb=16, l-tile=16, b=64); block computes 64 l x 64 h tile over K=1024,
// reduces the 64 h columns through tanh(q+.)*v, atomicAdds into score[b,l].
__global__ __launch_bounds__(256) void k2_scores(
    const float* __restrict__ keys, const float* __restrict__ W2,
    const float* __restrict__ v, float* __restrict__ out)
{
    __shared__ float As[32][64];    // [k][l]
    __shared__ float Bs[32][64];    // [k][h]
    __shared__ float red[64][16];
    const int t  = threadIdx.x;
    const int tx = t & 15, ty = t >> 4;
    const int hb = blockIdx.x;
    const int l0 = blockIdx.y * 64;
    const int b  = blockIdx.z;
    const int h0 = hb * 64;
    const float* qws = out;                   // q written by k1
    float* score = out + 65536;               // zeroed by k1
    const float* Ag = keys + ((size_t)b * 1024 + (size_t)l0) * 1024;
    const float* Bg = W2 + (size_t)h0 * 1024;
    const int sr = t >> 2;
    const int sk = (t & 3) * 8;
    float c[4][4] = {{0.f}};
    for (int k0 = 0; k0 < 1024; k0 += 32) {
        const float4 a0 = *(const float4*)(Ag + (size_t)sr * 1024 + k0 + sk);
        const float4 a1 = *(const float4*)(Ag + (size_t)sr * 1024 + k0 + sk + 4);
        const float4 b0 = *(const float4*)(Bg + (size_t)sr * 1024 + k0 + sk);
        const float4 b1 = *(const float4*)(Bg + (size_t)sr * 1024 + k0 + sk + 4);
        __syncthreads();
        As[sk+0][sr]=a0.x; As[sk+1][sr]=a0.y; As[sk+2][sr]=a0.z; As[sk+3][sr]=a0.w;
        As[sk+4][sr]=a1.x; As[sk+5][sr]=a1.y; As[sk+6][sr]=a1.z; As[sk+7][sr]=a1.w;
        Bs[sk+0][sr]=b0.x; Bs[sk+1][sr]=b0.y; Bs[sk+2][sr]=b0.z; Bs[sk+3][sr]=b0.w;
        Bs[sk+4][sr]=b1.x; Bs[sk+5][sr]=b1.y; Bs[sk+6][sr]=b1.z; Bs[sk+7][sr]=b1.w;
        __syncthreads();
        #pragma unroll
        for (int k = 0; k < 32; ++k) {
            const float4 av = *(const float4*)&As[k][ty*4];
            const float4 bv = *(const float4*)&Bs[k][tx*4];
            const float aa[4] = {av.x, av.y, av.z, av.w};
            const float bb[4] = {bv.x, bv.y, bv.z, bv.w};
            #pragma unroll
            for (int i = 0; i < 4; ++i)
                #pragma unroll
                for (int j = 0; j < 4; ++j)
                    c[i][j] = fmaf(aa[i], bb[j], c[i][j]);
        }
    }
    // epilogue: tanh(q + c) * v, reduce over this block's 64 h columns
    float qv[4], vv[4];
    #pragma unroll
    for (int j = 0; j < 4; ++j) {
        const int h = h0 + tx*4 + j;
        qv[j] = qws[b * 1024 + h];
        vv[j] = v[h];
    }
    float p[4];
    #pragma unroll
    for (int i = 0; i < 4; ++i) {
        float s = 0.f;
        #pragma unroll
        for (int j = 0; j < 4; ++j)
            s += tanhf(qv[j] + c[i][j]) * vv[j];
        p[i] = s;
    }
    __syncthreads();
    #pragma unroll
    for (int i = 0; i < 4; ++i) red[ty*4 + i][tx] = p[i];
    __syncthreads();
    if (t < 64) {
        const float* r = red[t];
        float s = 0.f;
        #pragma unroll
        for (int x = 0; x < 16; ++x) s += r[x];
        atomicAdd(&score[b * 1024 + l0 + t], s);   // accumulate over 16 hb blocks
    }
}

// --------- k3: mask, softmax in-place over score region; zero context row ---------
__global__ __launch_bounds__(256) void k3_softmax(
    const unsigned char* __restrict__ mask_u8, float* __restrict__ out)
{
    __shared__ float sc[1024];
    __shared__ float red[256];
    __shared__ int nz_sh;
    const int b = blockIdx.x;
    const int t = threadIdx.x;

    // inline mask-dtype sniff over the first 1024 bytes (safe for u8 or i32):
    // int32 0/1 data has zero bytes at positions i%4 != 0.
    if (t == 0) nz_sh = 0;
    __syncthreads();
    {
        int nz = 0;
        #pragma unroll
        for (int j = 1; j < 4; ++j)
            if (mask_u8[t * 4 + j] != 0) nz = 1;
        if (nz) atomicAdd(&nz_sh, 1);
    }
    __syncthreads();
    const int use_i32 = (nz_sh == 0);
    const int* mask_i32 = (const int*)mask_u8;

    float* score = out + 65536;
    float lmax = -INFINITY;
    #pragma unroll
    for (int i = 0; i < 4; ++i) {
        const int l = t + i * 256;
        float s = score[b * 1024 + l];
        const int ml = b * 1024 + l;
        const bool masked = use_i32 ? (mask_i32[ml] != 0) : (mask_u8[ml] != 0);
        if (masked) s = -INFINITY;   // where(mask, -inf, s)
        sc[l] = s;
        lmax = fmaxf(lmax, s);
    }
    red[t] = lmax;
    __syncthreads();
    for (int off = 128; off > 0; off >>= 1) {
        if (t < off) red[t] = fmaxf(red[t], red[t + off]);
        __syncthreads();
    }
    const float m = red[0];
    __syncthreads();
    float e[4];
    float lsum = 0.f;
    #pragma unroll
    for (int i = 0; i < 4; ++i) {
        const float s = sc[t + i * 256];
        const float ev = (s > -INFINITY && m > -INFINITY) ? expf(s - m) : 0.f;
        e[i] = ev;
        lsum += ev;
    }
    red[t] = lsum;
    __syncthreads();
    for (int off = 128; off > 0; off >>= 1) {
        if (t < off) red[t] += red[t + off];
        __syncthreads();
    }
    const float S = red[0];
    const float inv = (S > 0.f) ? (1.f / S) : 0.f;   // all-masked row -> weights 0 (nan_to_num)
    #pragma unroll
    for (int i = 0; i < 4; ++i)
        score[b * 1024 + t + i * 256] = e[i] * inv;  // weights, in place
    // zero context row (reclaims the q staging area) for k4's atomic accumulation
    const float4 z = {0.f, 0.f, 0.f, 0.f};
    ((float4*)(out + b * 1024))[t] = z;
}

// --------- k4: context[b,:] += sum over this block's 128 l's of w*keys ---------
__global__ __launch_bounds__(256) void k4_context(
    const float* __restrict__ keys, float* __restrict__ out)
{
    __shared__ float w[128];
    const int t  = threadIdx.x;
    const int b  = blockIdx.y;
    const int l0 = blockIdx.x * 128;
    if (t < 128) w[t] = out[65536 + b * 1024 + l0 + t];
    __syncthreads();
    const float4* kp = (const float4*)(keys + ((size_t)b * 1024 + (size_t)l0) * 1024) + t;
    float4 acc = {0.f, 0.f, 0.f, 0.f};
    #pragma unroll 4
    for (int l = 0; l < 128; ++l) {
        const float4 kv = kp[(size_t)l * 256];
        const float wv = w[l];
        acc.x = fmaf(wv, kv.x, acc.x);
        acc.y = fmaf(wv, kv.y, acc.y);
        acc.z = fmaf(wv, kv.z, acc.z);
        acc.w = fmaf(wv, kv.w, acc.w);
    }
    float* o = out + b * 1024 + t * 4;
    atomicAdd(o + 0, acc.x);
    atomicAdd(o + 1, acc.y);
    atomicAdd(o + 2, acc.z);
    atomicAdd(o + 3, acc.w);
}

extern "C" void kernel_launch(void* const* d_in, const int* in_sizes, int n_in,
                              void* d_out, int out_size, void* d_ws, size_t ws_size,
                              hipStream_t stream) {
    const float*         query = (const float*)d_in[0];
    const float*         keys  = (const float*)d_in[1];
    const unsigned char* mask  = (const unsigned char*)d_in[2];  // bool: u8 or i32, sniffed in k3
    const float*         W1    = (const float*)d_in[3];
    const float*         W2    = (const float*)d_in[4];
    const float*         v     = (const float*)d_in[5];
    float* out = (float*)d_out;   // [0..65536) context, [65536..131072) weights
    (void)d_ws; (void)ws_size;    // deliberately unused — no ws_size assumption

    k1_qproj  <<<dim3(16),          256, 0, stream>>>(query, W1, out);
    k2_scores <<<dim3(16, 16, 64),  256, 0, stream>>>(keys, W2, v, out);
    k3_softmax<<<dim3(64),          256, 0, stream>>>(mask, out);
    k4_context<<<dim3(8, 64),       256, 0, stream>>>(keys, out);
}

// Round 4
// 790.016 us; speedup vs baseline: 2.8372x; 2.8372x over previous
//
#include <hip/hip_runtime.h>
#include <math.h>

// AdditiveAttention: B=64, L=1024, Q=K=H=1024, fp32 in/out.
// Round 4: k2 (91% of runtime, was fp32-VALU-bound at 67 TF) moved to bf16 MFMA.
// Zero-workspace invariant kept: all intermediates live inside d_out.
//
//   out[0..65536):      k0 zeroes; k1 atomicAdds q = query@W1^T; k3 zeroes; k4 accumulates context.
//   out[65536..131072): k0 zeroes; k2 atomicAdds scores; k3 overwrites with softmax weights.
//
// k2: 65536x1024x1024 GEMM (keys @ W2^T) on mfma_f32_16x16x32_bf16, 128x128 tile,
//     BK=32, inline fp32->bf16 (RNE) conversion in LDS staging, fused tanh(q+.)·v epilogue.

typedef __attribute__((ext_vector_type(8))) short short8;   // 8 bf16 = 4 VGPRs (A/B frag)
typedef __attribute__((ext_vector_type(4))) float floatx4;  // 4 fp32 (C/D frag)

__device__ __forceinline__ short f2bf(float x) {            // fp32 -> bf16, round-nearest-even
    unsigned u = __float_as_uint(x);
    u += 0x7fffu + ((u >> 16) & 1u);
    return (short)(u >> 16);
}
__device__ __forceinline__ short8 pack8(float4 lo, float4 hi) {
    short8 r;
    r[0]=f2bf(lo.x); r[1]=f2bf(lo.y); r[2]=f2bf(lo.z); r[3]=f2bf(lo.w);
    r[4]=f2bf(hi.x); r[5]=f2bf(hi.y); r[6]=f2bf(hi.z); r[7]=f2bf(hi.w);
    return r;
}

#define LDA 40   // 32 k + 8 pad (shorts): breaks pow2 bank stride; 16B-aligned rows (80 B)

// ---------------- k0: zero the whole output buffer (131072 floats) ----------------
__global__ __launch_bounds__(256) void k0_zero(float* __restrict__ out) {
    const int i = (blockIdx.x * 256 + threadIdx.x) * 4;
    const float4 z = {0.f, 0.f, 0.f, 0.f};
    *(float4*)(out + i) = z;
}

// ------- k1: q += query @ W1^T (BM=64 b, BN=64 h, BK=32), K split x4, atomicAdd -------
__global__ __launch_bounds__(256) void k1_qproj(
    const float* __restrict__ query, const float* __restrict__ W1,
    float* __restrict__ out)
{
    __shared__ float As[32][64];   // [k][b]
    __shared__ float Bs[32][64];   // [k][h]
    const int t  = threadIdx.x;
    const int tx = t & 15, ty = t >> 4;
    const int h0 = blockIdx.x * 64;
    const int kbase = blockIdx.y * 256;
    const int sr = t >> 2;          // staging row 0..63
    const int sk = (t & 3) * 8;     // staging k offset {0,8,16,24}
    float c[4][4] = {{0.f}};
    for (int k0 = kbase; k0 < kbase + 256; k0 += 32) {
        const float4 a0 = *(const float4*)(query + sr * 1024 + k0 + sk);
        const float4 a1 = *(const float4*)(query + sr * 1024 + k0 + sk + 4);
        const float4 b0 = *(const float4*)(W1 + (h0 + sr) * 1024 + k0 + sk);
        const float4 b1 = *(const float4*)(W1 + (h0 + sr) * 1024 + k0 + sk + 4);
        __syncthreads();
        As[sk+0][sr]=a0.x; As[sk+1][sr]=a0.y; As[sk+2][sr]=a0.z; As[sk+3][sr]=a0.w;
        As[sk+4][sr]=a1.x; As[sk+5][sr]=a1.y; As[sk+6][sr]=a1.z; As[sk+7][sr]=a1.w;
        Bs[sk+0][sr]=b0.x; Bs[sk+1][sr]=b0.y; Bs[sk+2][sr]=b0.z; Bs[sk+3][sr]=b0.w;
        Bs[sk+4][sr]=b1.x; Bs[sk+5][sr]=b1.y; Bs[sk+6][sr]=b1.z; Bs[sk+7][sr]=b1.w;
        __syncthreads();
        #pragma unroll
        for (int k = 0; k < 32; ++k) {
            const float4 av = *(const float4*)&As[k][ty*4];
            const float4 bv = *(const float4*)&Bs[k][tx*4];
            const float aa[4] = {av.x, av.y, av.z, av.w};
            const float bb[4] = {bv.x, bv.y, bv.z, bv.w};
            #pragma unroll
            for (int i = 0; i < 4; ++i)
                #pragma unroll
                for (int j = 0; j < 4; ++j)
                    c[i][j] = fmaf(aa[i], bb[j], c[i][j]);
        }
    }
    #pragma unroll
    for (int i = 0; i < 4; ++i)
        #pragma unroll
        for (int j = 0; j < 4; ++j)
            atomicAdd(&out[(ty*4 + i) * 1024 + h0 + tx*4 + j], c[i][j]);
}

// --------- k2: bf16-MFMA keys@W2^T (128x128 tile) + fused tanh-dot-v epilogue ---------
// grid: (hb=8 fastest for A-tile L2 reuse, l-tile=8, b=64). Each block: 128 l x 128 h
// over K=1024; epilogue reduces its 128 h-cols via tanh(q+.)*v -> atomicAdd score[b,l].
__global__ __launch_bounds__(256) void k2_scores(
    const float* __restrict__ keys, const float* __restrict__ W2,
    const float* __restrict__ v, float* __restrict__ out)
{
    __shared__ union {
        struct { short A[128][LDA]; short B[128][LDA]; } st;  // 20.0 KB staging
        float red[128][33];                                    // 16.5 KB epilogue overlay
    } sm;
    const int t  = threadIdx.x;
    const int hb = blockIdx.x;          // 0..7
    const int l0 = blockIdx.y * 128;
    const int b  = blockIdx.z;
    const int h0 = hb * 128;
    const float* q = out;               // written by k1
    float* score = out + 65536;         // zeroed by k0

    // staging: thread t loads 16 fp32 of row (t>>1), k-half (t&1)*16, for both A and B
    const int srow = t >> 1;
    const int skh  = (t & 1) * 16;
    const float* Arow = keys + ((size_t)(b * 1024 + l0 + srow)) * 1024 + skh;
    const float* Brow = W2   + ((size_t)(h0 + srow)) * 1024 + skh;

    // MFMA lane mapping (verified m89/m91): A/B frag [lane&15][quad*8+j]; C/D col=lane&15,row=quad*4+reg
    const int lane = t & 63, wid = t >> 6;
    const int quad = lane >> 4, m16 = lane & 15;
    const int wm = (wid >> 1) * 64;     // wave's m (l) origin
    const int wn = (wid & 1) * 64;      // wave's n (h) origin

    floatx4 acc[4][4] = {};

    for (int kk = 0; kk < 1024; kk += 32) {
        const float4 a0 = *(const float4*)(Arow + kk);
        const float4 a1 = *(const float4*)(Arow + kk + 4);
        const float4 a2 = *(const float4*)(Arow + kk + 8);
        const float4 a3 = *(const float4*)(Arow + kk + 12);
        const float4 w0 = *(const float4*)(Brow + kk);
        const float4 w1 = *(const float4*)(Brow + kk + 4);
        const float4 w2 = *(const float4*)(Brow + kk + 8);
        const float4 w3 = *(const float4*)(Brow + kk + 12);
        __syncthreads();   // prior iteration's frag reads complete before overwrite
        *(short8*)&sm.st.A[srow][skh]     = pack8(a0, a1);
        *(short8*)&sm.st.A[srow][skh + 8] = pack8(a2, a3);
        *(short8*)&sm.st.B[srow][skh]     = pack8(w0, w1);
        *(short8*)&sm.st.B[srow][skh + 8] = pack8(w2, w3);
        __syncthreads();
        short8 af[4], bf[4];
        #pragma unroll
        for (int i = 0; i < 4; ++i)
            af[i] = *(const short8*)&sm.st.A[wm + i*16 + m16][quad * 8];
        #pragma unroll
        for (int j = 0; j < 4; ++j)
            bf[j] = *(const short8*)&sm.st.B[wn + j*16 + m16][quad * 8];
        #pragma unroll
        for (int i = 0; i < 4; ++i)
            #pragma unroll
            for (int j = 0; j < 4; ++j)
                acc[i][j] = __builtin_amdgcn_mfma_f32_16x16x32_bf16(af[i], bf[j], acc[i][j], 0, 0, 0);
    }

    // epilogue: s[l] = sum_h tanh(q[b,h] + D[l,h]) * v[h] over this block's 128 h
    float qv[4], vv[4];
    #pragma unroll
    for (int j = 0; j < 4; ++j) {
        const int h = h0 + wn + j * 16 + m16;   // C/D col for n-tile j
        qv[j] = q[b * 1024 + h];
        vv[j] = v[h];
    }
    __syncthreads();   // staging reads done before red overlay
    #pragma unroll
    for (int i = 0; i < 4; ++i) {
        #pragma unroll
        for (int r = 0; r < 4; ++r) {
            float s = 0.f;
            #pragma unroll
            for (int j = 0; j < 4; ++j)
                s += tanhf(qv[j] + acc[i][j][r]) * vv[j];
            // C/D row for m-tile i, reg r: wm + i*16 + quad*4 + r
            sm.red[wm + i * 16 + quad * 4 + r][(wid & 1) * 16 + m16] = s;
        }
    }
    __syncthreads();
    if (t < 128) {
        const float* rr = sm.red[t];
        float s = 0.f;
        #pragma unroll
        for (int c = 0; c < 32; ++c) s += rr[c];
        atomicAdd(&score[b * 1024 + l0 + t], s);   // accumulate over 8 hb blocks
    }
}

// --------- k3: mask, softmax in-place over score region; zero context row ---------
__global__ __launch_bounds__(256) void k3_softmax(
    const unsigned char* __restrict__ mask_u8, float* __restrict__ out)
{
    __shared__ float sc[1024];
    __shared__ float red[256];
    __shared__ int nz_sh;
    const int b = blockIdx.x;
    const int t = threadIdx.x;

    // inline mask-dtype sniff over the first 1024 bytes (safe for u8 or i32):
    // int32 0/1 data has zero bytes at positions i%4 != 0.
    if (t == 0) nz_sh = 0;
    __syncthreads();
    {
        int nz = 0;
        #pragma unroll
        for (int j = 1; j < 4; ++j)
            if (mask_u8[t * 4 + j] != 0) nz = 1;
        if (nz) atomicAdd(&nz_sh, 1);
    }
    __syncthreads();
    const int use_i32 = (nz_sh == 0);
    const int* mask_i32 = (const int*)mask_u8;

    float* score = out + 65536;
    float lmax = -INFINITY;
    #pragma unroll
    for (int i = 0; i < 4; ++i) {
        const int l = t + i * 256;
        float s = score[b * 1024 + l];
        const int ml = b * 1024 + l;
        const bool masked = use_i32 ? (mask_i32[ml] != 0) : (mask_u8[ml] != 0);
        if (masked) s = -INFINITY;   // where(mask, -inf, s)
        sc[l] = s;
        lmax = fmaxf(lmax, s);
    }
    red[t] = lmax;
    __syncthreads();
    for (int off = 128; off > 0; off >>= 1) {
        if (t < off) red[t] = fmaxf(red[t], red[t + off]);
        __syncthreads();
    }
    const float m = red[0];
    __syncthreads();
    float e[4];
    float lsum = 0.f;
    #pragma unroll
    for (int i = 0; i < 4; ++i) {
        const float s = sc[t + i * 256];
        const float ev = (s > -INFINITY && m > -INFINITY) ? expf(s - m) : 0.f;
        e[i] = ev;
        lsum += ev;
    }
    red[t] = lsum;
    __syncthreads();
    for (int off = 128; off > 0; off >>= 1) {
        if (t < off) red[t] += red[t + off];
        __syncthreads();
    }
    const float S = red[0];
    const float inv = (S > 0.f) ? (1.f / S) : 0.f;   // all-masked row -> weights 0 (nan_to_num)
    #pragma unroll
    for (int i = 0; i < 4; ++i)
        score[b * 1024 + t + i * 256] = e[i] * inv;  // weights, in place
    // zero context row (reclaims the q staging area) for k4's atomic accumulation
    const float4 z = {0.f, 0.f, 0.f, 0.f};
    ((float4*)(out + b * 1024))[t] = z;
}

// --------- k4: context[b,:] += sum over this block's 128 l's of w*keys ---------
__global__ __launch_bounds__(256) void k4_context(
    const float* __restrict__ keys, float* __restrict__ out)
{
    __shared__ float w[128];
    const int t  = threadIdx.x;
    const int b  = blockIdx.y;
    const int l0 = blockIdx.x * 128;
    if (t < 128) w[t] = out[65536 + b * 1024 + l0 + t];
    __syncthreads();
    const float4* kp = (const float4*)(keys + ((size_t)b * 1024 + (size_t)l0) * 1024) + t;
    float4 acc = {0.f, 0.f, 0.f, 0.f};
    #pragma unroll 4
    for (int l = 0; l < 128; ++l) {
        const float4 kv = kp[(size_t)l * 256];
        const float wv = w[l];
        acc.x = fmaf(wv, kv.x, acc.x);
        acc.y = fmaf(wv, kv.y, acc.y);
        acc.z = fmaf(wv, kv.z, acc.z);
        acc.w = fmaf(wv, kv.w, acc.w);
    }
    float* o = out + b * 1024 + t * 4;
    atomicAdd(o + 0, acc.x);
    atomicAdd(o + 1, acc.y);
    atomicAdd(o + 2, acc.z);
    atomicAdd(o + 3, acc.w);
}

extern "C" void kernel_launch(void* const* d_in, const int* in_sizes, int n_in,
                              void* d_out, int out_size, void* d_ws, size_t ws_size,
                              hipStream_t stream) {
    const float*         query = (const float*)d_in[0];
    const float*         keys  = (const float*)d_in[1];
    const unsigned char* mask  = (const unsigned char*)d_in[2];  // bool: u8 or i32, sniffed in k3
    const float*         W1    = (const float*)d_in[3];
    const float*         W2    = (const float*)d_in[4];
    const float*         v     = (const float*)d_in[5];
    float* out = (float*)d_out;   // [0..65536) context, [65536..131072) weights
    (void)d_ws; (void)ws_size;    // deliberately unused — no ws_size assumption

    k0_zero   <<<dim3(128),       256, 0, stream>>>(out);
    k1_qproj  <<<dim3(16, 4),     256, 0, stream>>>(query, W1, out);
    k2_scores <<<dim3(8, 8, 64),  256, 0, stream>>>(keys, W2, v, out);
    k3_softmax<<<dim3(64),        256, 0, stream>>>(mask, out);
    k4_context<<<dim3(8, 64),     256, 0, stream>>>(keys, out);
}